// Round 2
// baseline (465.187 us; speedup 1.0000x reference)
//
#include <hip/hip_runtime.h>
#include <math.h>

typedef unsigned short u16;
typedef __bf16 bf16x8 __attribute__((ext_vector_type(8)));
typedef u16    u16x8  __attribute__((ext_vector_type(8)));
typedef float  f32x4  __attribute__((ext_vector_type(4)));

__device__ __forceinline__ float b2f(u16 u) {
    union { unsigned u; float f; } x; x.u = ((unsigned)u) << 16; return x.f;
}
__device__ __forceinline__ u16 f2b(float f) {
    union { float f; unsigned u; } x; x.f = f;
    unsigned r = x.u + 0x7FFFu + ((x.u >> 16) & 1u);   // RNE
    return (u16)(r >> 16);
}
__device__ __forceinline__ f32x4 mfma16(bf16x8 a, bf16x8 b, f32x4 c) {
    return __builtin_amdgcn_mfma_f32_16x16x32_bf16(a, b, c, 0, 0, 0);
}

// ---------------------------------------------------------------- dtype detector
// Low u16 of each 32-bit word: bf16 buffer -> valid bf16 exponent (~99%);
// fp32 buffer -> random mantissa bits (~19% in range). flag: 0=bf16, 1=fp32.
__global__ __launch_bounds__(256) void k_detect(const unsigned* __restrict__ x32, int* __restrict__ flag) {
    __shared__ int cnt;
    if (threadIdx.x == 0) cnt = 0;
    __syncthreads();
    int local = 0;
    for (int i = threadIdx.x; i < 4096; i += 256) {
        unsigned lo = x32[i] & 0xFFFFu;
        unsigned e = (lo >> 7) & 0xFFu;
        if (e >= 0x60u && e <= 0x8Fu) local++;
    }
    atomicAdd(&cnt, local);
    __syncthreads();
    if (threadIdx.x == 0) *flag = (cnt >= 2048) ? 0 : 1;
}

// ---------------------------------------------------------------- input convert -> bf16 workspace
__global__ __launch_bounds__(256) void k_cvt(const void* __restrict__ src, u16* __restrict__ dst,
                                             int n, const int* __restrict__ flag) {
    const int i = blockIdx.x * 256 + threadIdx.x;
    if (i >= n) return;
    if (*flag) dst[i] = f2b(((const float*)src)[i]);
    else       dst[i] = ((const u16*)src)[i];
}

// ---------------------------------------------------------------- group-norm stats
__global__ __launch_bounds__(256) void k_stats(const u16* __restrict__ x, float* __restrict__ stats) {
    const int bg = blockIdx.x;
    const u16* p = x + (size_t)bg * 131072;
    float s = 0.f, ss = 0.f;
    for (int i = threadIdx.x; i < 16384; i += 256) {
        bf16x8 v = *(const bf16x8*)(p + i * 8);
#pragma unroll
        for (int j = 0; j < 8; j++) { float f = (float)v[j]; s += f; ss += f * f; }
    }
#pragma unroll
    for (int o = 1; o < 64; o <<= 1) { s += __shfl_xor(s, o, 64); ss += __shfl_xor(ss, o, 64); }
    __shared__ float rs[4], rss[4];
    const int wv = threadIdx.x >> 6;
    if ((threadIdx.x & 63) == 0) { rs[wv] = s; rss[wv] = ss; }
    __syncthreads();
    if (threadIdx.x == 0) {
        s = rs[0] + rs[1] + rs[2] + rs[3];
        ss = rss[0] + rss[1] + rss[2] + rss[3];
        float mean = s * (1.f / 131072.f);
        float var = fmaxf(ss * (1.f / 131072.f) - mean * mean, 0.f);
        stats[bg] = mean;
        stats[32 + bg] = rsqrtf(var + 1e-5f);
    }
}

// ---------------------------------------------------------------- normalize + transpose to tokens [b][n][c]
__global__ __launch_bounds__(256) void k_tok(const u16* __restrict__ x, const u16* __restrict__ nw,
                                             const u16* __restrict__ nb, const float* __restrict__ stats,
                                             u16* __restrict__ tok) {
    const int b = blockIdx.z, c0 = blockIdx.y * 64, p0 = blockIdx.x * 64;
    __shared__ u16 t[64][72];
    const int cl = threadIdx.x >> 2, seg = threadIdx.x & 3;
    const int c = c0 + cl;
    const int g = c >> 5;
    const float mean = stats[b * 8 + g], rstd = stats[32 + b * 8 + g];
    const float scale = b2f(nw[c]) * rstd;
    const float shift = b2f(nb[c]) - mean * scale;
    const u16* xp = x + ((size_t)(b * 256 + c)) * 4096 + p0 + seg * 16;
#pragma unroll
    for (int h = 0; h < 2; h++) {
        bf16x8 v = *(const bf16x8*)(xp + h * 8);
#pragma unroll
        for (int j = 0; j < 8; j++)
            t[seg * 16 + h * 8 + j][cl] = f2b((float)v[j] * scale + shift);
    }
    __syncthreads();
    u16x8 o0, o1;
#pragma unroll
    for (int j = 0; j < 8; j++) { o0[j] = t[cl][seg * 16 + j]; o1[j] = t[cl][seg * 16 + 8 + j]; }
    u16* op = tok + ((size_t)(b * 4096 + p0 + cl)) * 256 + c0 + seg * 16;
    *(u16x8*)op = o0;
    *((u16x8*)op + 1) = o1;
}

// ---------------------------------------------------------------- QKV GEMM
__global__ __launch_bounds__(256) void k_qkv(const u16* __restrict__ A, const u16* __restrict__ W,
                                             const u16* __restrict__ bias,
                                             u16* __restrict__ Qo, u16* __restrict__ Ko, u16* __restrict__ Vt) {
    const int m0 = blockIdx.x * 128, n0 = blockIdx.y * 128;
    const int tid = threadIdx.x, w = tid >> 6, lane = tid & 63, l15 = lane & 15, l4 = lane >> 4;
    const int wm = w >> 1, wn = w & 1;
    __shared__ __attribute__((aligned(16))) u16 At[128 * 64];
    __shared__ __attribute__((aligned(16))) u16 Bt[128 * 64];
    f32x4 acc[4][4];
    const f32x4 z = {0.f, 0.f, 0.f, 0.f};
#pragma unroll
    for (int i = 0; i < 4; i++)
#pragma unroll
        for (int j = 0; j < 4; j++) acc[i][j] = z;

    for (int kt = 0; kt < 4; kt++) {
        const int k0 = kt * 64;
#pragma unroll
        for (int i = 0; i < 4; i++) {
            int v = tid + i * 256;
            int row = v >> 3, c8 = v & 7;
            *(u16x8*)(&At[row * 64 + c8 * 8]) = *(const u16x8*)(A + (size_t)(m0 + row) * 256 + k0 + c8 * 8);
            *(u16x8*)(&Bt[row * 64 + c8 * 8]) = *(const u16x8*)(W + (size_t)(n0 + row) * 256 + k0 + c8 * 8);
        }
        __syncthreads();
#pragma unroll
        for (int ks = 0; ks < 2; ks++) {
            bf16x8 af[4], bfr[4];
#pragma unroll
            for (int i = 0; i < 4; i++) {
                af[i]  = *(const bf16x8*)(&At[(wm * 64 + i * 16 + l15) * 64 + ks * 32 + l4 * 8]);
                bfr[i] = *(const bf16x8*)(&Bt[(wn * 64 + i * 16 + l15) * 64 + ks * 32 + l4 * 8]);
            }
#pragma unroll
            for (int i = 0; i < 4; i++)
#pragma unroll
                for (int j = 0; j < 4; j++) acc[i][j] = mfma16(af[i], bfr[j], acc[i][j]);
        }
        __syncthreads();
    }
#pragma unroll
    for (int j = 0; j < 4; j++) {
        const int n = n0 + wn * 64 + j * 16 + l15;
        const float bia = b2f(bias[n]);
#pragma unroll
        for (int i = 0; i < 4; i++) {
#pragma unroll
            for (int r = 0; r < 4; r++) {
                const int m = m0 + wm * 64 + i * 16 + l4 * 4 + r;
                const float vv = acc[i][j][r] + bia;
                if (n < 256)       Qo[(size_t)m * 256 + n] = f2b(vv);
                else if (n < 512)  Ko[(size_t)m * 256 + (n - 256)] = f2b(vv);
                else {
                    const int bb = m >> 12, p = m & 4095;
                    Vt[((size_t)bb * 256 + (n - 512)) * 4096 + p] = f2b(vv);
                }
            }
        }
    }
}

// ---------------------------------------------------------------- flash attention
__global__ __launch_bounds__(256) void k_attn(const u16* __restrict__ Q, const u16* __restrict__ K,
                                              const u16* __restrict__ Vt, u16* __restrict__ O) {
    const int qt = blockIdx.x, b = blockIdx.y;
    const int tid = threadIdx.x, w = tid >> 6, lane = tid & 63, l15 = lane & 15, l4 = lane >> 4;
    const int srow = lane >> 2, sseg = lane & 3;
    const int qw0 = qt * 64 + w * 16;

    __shared__ __attribute__((aligned(16))) u16 Kt[64 * 256];
    __shared__ __attribute__((aligned(16))) u16 Vtile[256 * 64];
    __shared__ __attribute__((aligned(16))) float Sb[4][16 * 64];
    __shared__ __attribute__((aligned(16))) u16 Pb[4][16 * 64];
    __shared__ float aB[4][16];
    __shared__ float lB[4][16];

    bf16x8 aq[8];
    const u16* qp = Q + ((size_t)(b * 4096 + qw0 + l15)) * 256 + l4 * 8;
#pragma unroll
    for (int kb = 0; kb < 8; kb++) aq[kb] = *(const bf16x8*)(qp + kb * 32);

    f32x4 acc[16];
    const f32x4 z = {0.f, 0.f, 0.f, 0.f};
#pragma unroll
    for (int i = 0; i < 16; i++) acc[i] = z;
    float m_i = -1e30f, l_i = 0.f;

    for (int kt = 0; kt < 64; kt++) {
        const int j0 = kt * 64;
#pragma unroll
        for (int i = 0; i < 8; i++) {
            int v = tid + i * 256;
            int row = v >> 5, c8 = v & 31;
            *(u16x8*)(&Kt[row * 256 + c8 * 8]) =
                *(const u16x8*)(K + ((size_t)(b * 4096 + j0 + row)) * 256 + c8 * 8);
        }
#pragma unroll
        for (int i = 0; i < 8; i++) {
            int v = tid + i * 256;
            int c = v >> 3, c8 = v & 7;
            *(u16x8*)(&Vtile[c * 64 + c8 * 8]) =
                *(const u16x8*)(Vt + ((size_t)(b * 256 + c)) * 4096 + j0 + c8 * 8);
        }
        __syncthreads();   // (A) tiles staged

        // S = Q K^T
#pragma unroll
        for (int nt = 0; nt < 4; nt++) {
            f32x4 s = z;
#pragma unroll
            for (int kb = 0; kb < 8; kb++) {
                bf16x8 bk = *(const bf16x8*)(&Kt[(nt * 16 + l15) * 256 + kb * 32 + l4 * 8]);
                s = mfma16(aq[kb], bk, s);
            }
#pragma unroll
            for (int r = 0; r < 4; r++)
                Sb[w][(l4 * 4 + r) * 64 + nt * 16 + l15] = s[r] * 0.0625f;
        }
        __syncthreads();   // (B) S visible

        // online softmax: 4 lanes per row
        float px[16];
        float mx = -1e30f;
#pragma unroll
        for (int j = 0; j < 16; j++) { px[j] = Sb[w][srow * 64 + sseg * 16 + j]; mx = fmaxf(mx, px[j]); }
        mx = fmaxf(mx, __shfl_xor(mx, 1, 64));
        mx = fmaxf(mx, __shfl_xor(mx, 2, 64));
        const float m_new = fmaxf(m_i, mx);
        const float alpha = __expf(fminf(m_i - m_new, 0.f));
        float sum = 0.f;
#pragma unroll
        for (int j = 0; j < 16; j++) {
            float e = __expf(fminf(px[j] - m_new, 0.f));
            sum += e;
            Pb[w][srow * 64 + sseg * 16 + j] = f2b(e);
        }
        sum += __shfl_xor(sum, 1, 64);
        sum += __shfl_xor(sum, 2, 64);
        l_i = l_i * alpha + sum;
        m_i = m_new;
        if (sseg == 0) aB[w][srow] = alpha;
        __syncthreads();   // (C) P, alpha visible

        float ar[4];
#pragma unroll
        for (int r = 0; r < 4; r++) ar[r] = aB[w][l4 * 4 + r];
#pragma unroll
        for (int nt = 0; nt < 16; nt++)
#pragma unroll
            for (int r = 0; r < 4; r++) acc[nt][r] *= ar[r];
#pragma unroll
        for (int ks = 0; ks < 2; ks++) {
            bf16x8 ap = *(const bf16x8*)(&Pb[w][l15 * 64 + ks * 32 + l4 * 8]);
#pragma unroll
            for (int nt = 0; nt < 16; nt++) {
                bf16x8 bv = *(const bf16x8*)(&Vtile[(nt * 16 + l15) * 64 + ks * 32 + l4 * 8]);
                acc[nt] = mfma16(ap, bv, acc[nt]);
            }
        }
        __syncthreads();   // (D) done with tiles
    }

    if (sseg == 0) lB[w][srow] = l_i;
    __syncthreads();
    float invl[4];
#pragma unroll
    for (int r = 0; r < 4; r++) invl[r] = 1.0f / fmaxf(lB[w][l4 * 4 + r], 1e-30f);
#pragma unroll
    for (int nt = 0; nt < 16; nt++) {
        const int col = nt * 16 + l15;
#pragma unroll
        for (int r = 0; r < 4; r++) {
            const int rowg = qw0 + l4 * 4 + r;
            O[((size_t)(b * 4096 + rowg)) * 256 + col] = f2b(acc[nt][r] * invl[r]);
        }
    }
}

// ---------------------------------------------------------------- proj GEMM + residual, store [b][c][p]
__global__ __launch_bounds__(256) void k_proj(const u16* __restrict__ A, const u16* __restrict__ W,
                                              const u16* __restrict__ bias, const u16* __restrict__ x,
                                              void* __restrict__ out, const int* __restrict__ flag) {
    const int f32out = *flag;
    const int m0 = blockIdx.x * 128, n0 = blockIdx.y * 128;
    const int tid = threadIdx.x, w = tid >> 6, lane = tid & 63, l15 = lane & 15, l4 = lane >> 4;
    const int wm = w >> 1, wn = w & 1;
    __shared__ __attribute__((aligned(16))) u16 At[128 * 64];
    __shared__ __attribute__((aligned(16))) u16 Bt[128 * 64];
    f32x4 acc[4][4];
    const f32x4 z = {0.f, 0.f, 0.f, 0.f};
#pragma unroll
    for (int i = 0; i < 4; i++)
#pragma unroll
        for (int j = 0; j < 4; j++) acc[i][j] = z;

    for (int kt = 0; kt < 4; kt++) {
        const int k0 = kt * 64;
#pragma unroll
        for (int i = 0; i < 4; i++) {
            int v = tid + i * 256;
            int row = v >> 3, c8 = v & 7;
            *(u16x8*)(&At[row * 64 + c8 * 8]) = *(const u16x8*)(A + (size_t)(m0 + row) * 256 + k0 + c8 * 8);
            *(u16x8*)(&Bt[row * 64 + c8 * 8]) = *(const u16x8*)(W + (size_t)(n0 + row) * 256 + k0 + c8 * 8);
        }
        __syncthreads();
#pragma unroll
        for (int ks = 0; ks < 2; ks++) {
            bf16x8 af[4], bfr[4];
#pragma unroll
            for (int i = 0; i < 4; i++) {
                af[i]  = *(const bf16x8*)(&At[(wm * 64 + i * 16 + l15) * 64 + ks * 32 + l4 * 8]);
                bfr[i] = *(const bf16x8*)(&Bt[(wn * 64 + i * 16 + l15) * 64 + ks * 32 + l4 * 8]);
            }
#pragma unroll
            for (int i = 0; i < 4; i++)
#pragma unroll
                for (int j = 0; j < 4; j++) acc[i][j] = mfma16(af[i], bfr[j], acc[i][j]);
        }
        __syncthreads();
    }
#pragma unroll
    for (int j = 0; j < 4; j++) {
        const int n = n0 + wn * 64 + j * 16 + l15;
        const float bia = b2f(bias[n]);
#pragma unroll
        for (int i = 0; i < 4; i++) {
#pragma unroll
            for (int r = 0; r < 4; r++) {
                const int m = m0 + wm * 64 + i * 16 + l4 * 4 + r;
                const int bb = m >> 12, p = m & 4095;
                const size_t oi = ((size_t)bb * 256 + n) * 4096 + p;
                const float v = b2f(x[oi]) + acc[i][j][r] + bia;
                if (f32out) ((float*)out)[oi] = v;
                else        ((u16*)out)[oi] = f2b(v);
            }
        }
    }
}

extern "C" void kernel_launch(void* const* d_in, const int* in_sizes, int n_in,
                              void* d_out, int out_size, void* d_ws, size_t ws_size,
                              hipStream_t stream) {
    char* ws = (char*)d_ws;
    float* stats = (float*)ws;                                   // 256 B
    int*   flag  = (int*)(ws + 2048);
    u16* xb  = (u16*)(ws + 4096);                                // 4194304 u16
    u16* nwb = xb + (size_t)4194304;                             // 256
    u16* nbb = nwb + 256;                                        // 256
    u16* qbb = nbb + 256;                                        // 768
    u16* pbb = qbb + 768;                                        // 256
    u16* pad = pbb + 256;                                        // align to 16B: total so far even
    u16* qwb = pad + 256;                                        // 196608
    u16* pwb = qwb + (size_t)196608;                             // 65536
    u16* tok = pwb + (size_t)65536;                              // [16384][256], reused as Ob
    u16* Qb  = tok + (size_t)16384 * 256;
    u16* Kb  = Qb  + (size_t)16384 * 256;
    u16* Vb  = Kb  + (size_t)16384 * 256;                        // [4][256][4096]
    u16* Ob  = tok;                                              // reuse

    k_detect<<<dim3(1), dim3(256), 0, stream>>>((const unsigned*)d_in[0], flag);
    k_cvt<<<dim3(16384), dim3(256), 0, stream>>>(d_in[0], xb,  4194304, flag);
    k_cvt<<<dim3(1),     dim3(256), 0, stream>>>(d_in[1], nwb, 256,     flag);
    k_cvt<<<dim3(1),     dim3(256), 0, stream>>>(d_in[2], nbb, 256,     flag);
    k_cvt<<<dim3(768),   dim3(256), 0, stream>>>(d_in[3], qwb, 196608,  flag);
    k_cvt<<<dim3(3),     dim3(256), 0, stream>>>(d_in[4], qbb, 768,     flag);
    k_cvt<<<dim3(256),   dim3(256), 0, stream>>>(d_in[5], pwb, 65536,   flag);
    k_cvt<<<dim3(1),     dim3(256), 0, stream>>>(d_in[6], pbb, 256,     flag);

    k_stats<<<dim3(32), dim3(256), 0, stream>>>(xb, stats);
    k_tok  <<<dim3(64, 4, 4), dim3(256), 0, stream>>>(xb, nwb, nbb, stats, tok);
    k_qkv  <<<dim3(128, 6), dim3(256), 0, stream>>>(tok, qwb, qbb, Qb, Kb, Vb);
    k_attn <<<dim3(64, 4), dim3(256), 0, stream>>>(Qb, Kb, Vb, Ob);
    k_proj <<<dim3(128, 2), dim3(256), 0, stream>>>(Ob, pwb, pbb, xb, d_out, flag);
}

// Round 3
// 420.105 us; speedup vs baseline: 1.1073x; 1.1073x over previous
//
#include <hip/hip_runtime.h>
#include <math.h>

typedef unsigned short u16;
typedef __bf16 bf16x8 __attribute__((ext_vector_type(8)));
typedef u16    u16x8  __attribute__((ext_vector_type(8)));
typedef float  f32x4  __attribute__((ext_vector_type(4)));

__device__ __forceinline__ float b2f(u16 u) {
    union { unsigned u; float f; } x; x.u = ((unsigned)u) << 16; return x.f;
}
__device__ __forceinline__ u16 f2b(float f) {
    union { float f; unsigned u; } x; x.f = f;
    unsigned r = x.u + 0x7FFFu + ((x.u >> 16) & 1u);   // RNE
    return (u16)(r >> 16);
}
__device__ __forceinline__ f32x4 mfma16(bf16x8 a, bf16x8 b, f32x4 c) {
    return __builtin_amdgcn_mfma_f32_16x16x32_bf16(a, b, c, 0, 0, 0);
}
__device__ __forceinline__ void dma16(const void* g, void* l) {
    __builtin_amdgcn_global_load_lds((const __attribute__((address_space(1))) void*)g,
                                     (__attribute__((address_space(3))) void*)l, 16, 0, 0);
}

// ---------------------------------------------------------------- dtype detector
__global__ __launch_bounds__(256) void k_detect(const unsigned* __restrict__ x32, int* __restrict__ flag) {
    __shared__ int cnt;
    if (threadIdx.x == 0) cnt = 0;
    __syncthreads();
    int local = 0;
    for (int i = threadIdx.x; i < 4096; i += 256) {
        unsigned lo = x32[i] & 0xFFFFu;
        unsigned e = (lo >> 7) & 0xFFu;
        if (e >= 0x60u && e <= 0x8Fu) local++;
    }
    atomicAdd(&cnt, local);
    __syncthreads();
    if (threadIdx.x == 0) *flag = (cnt >= 2048) ? 0 : 1;
}

// ---------------------------------------------------------------- x convert (x4 vectorized)
__global__ __launch_bounds__(256) void k_cvtx(const void* __restrict__ src, u16* __restrict__ dst,
                                              const int* __restrict__ flag) {
    const int i = (blockIdx.x * 256 + threadIdx.x) * 4;
    if (*flag) {
        float4 v = *(const float4*)((const float*)src + i);
        u16 o0 = f2b(v.x), o1 = f2b(v.y), o2 = f2b(v.z), o3 = f2b(v.w);
        unsigned lo = (unsigned)o0 | ((unsigned)o1 << 16);
        unsigned hi = (unsigned)o2 | ((unsigned)o3 << 16);
        *(uint2*)(dst + i) = make_uint2(lo, hi);
    } else {
        *(uint2*)(dst + i) = *(const uint2*)((const u16*)src + i);
    }
}

// ---------------------------------------------------------------- params convert (one launch)
__global__ __launch_bounds__(256) void k_cvtp(const void* s0, const void* s1, const void* s2,
                                              const void* s3, const void* s4, const void* s5,
                                              u16* d0, u16* d1, u16* d2, u16* d3, u16* d4, u16* d5,
                                              const int* __restrict__ flag) {
    const int i = blockIdx.x * 256 + threadIdx.x;
    const int f = *flag;
    const void* s; u16* d; int j;
    if      (i < 256)    { s = s0; d = d0; j = i; }
    else if (i < 512)    { s = s1; d = d1; j = i - 256; }
    else if (i < 197120) { s = s2; d = d2; j = i - 512; }
    else if (i < 197888) { s = s3; d = d3; j = i - 197120; }
    else if (i < 263424) { s = s4; d = d4; j = i - 197888; }
    else if (i < 263680) { s = s5; d = d5; j = i - 263424; }
    else return;
    if (f) d[j] = f2b(((const float*)s)[j]);
    else   d[j] = ((const u16*)s)[j];
}

// ---------------------------------------------------------------- group-norm stats
__global__ __launch_bounds__(256) void k_stats(const u16* __restrict__ x, float* __restrict__ stats) {
    const int bg = blockIdx.x;
    const u16* p = x + (size_t)bg * 131072;
    float s = 0.f, ss = 0.f;
    for (int i = threadIdx.x; i < 16384; i += 256) {
        bf16x8 v = *(const bf16x8*)(p + i * 8);
#pragma unroll
        for (int j = 0; j < 8; j++) { float f = (float)v[j]; s += f; ss += f * f; }
    }
#pragma unroll
    for (int o = 1; o < 64; o <<= 1) { s += __shfl_xor(s, o, 64); ss += __shfl_xor(ss, o, 64); }
    __shared__ float rs[4], rss[4];
    const int wv = threadIdx.x >> 6;
    if ((threadIdx.x & 63) == 0) { rs[wv] = s; rss[wv] = ss; }
    __syncthreads();
    if (threadIdx.x == 0) {
        s = rs[0] + rs[1] + rs[2] + rs[3];
        ss = rss[0] + rss[1] + rss[2] + rss[3];
        float mean = s * (1.f / 131072.f);
        float var = fmaxf(ss * (1.f / 131072.f) - mean * mean, 0.f);
        stats[bg] = mean;
        stats[32 + bg] = rsqrtf(var + 1e-5f);
    }
}

// ---------------------------------------------------------------- normalize + transpose to tokens [b][n][c]
__global__ __launch_bounds__(256) void k_tok(const u16* __restrict__ x, const u16* __restrict__ nw,
                                             const u16* __restrict__ nb, const float* __restrict__ stats,
                                             u16* __restrict__ tok) {
    const int b = blockIdx.z, c0 = blockIdx.y * 64, p0 = blockIdx.x * 64;
    __shared__ u16 t[64][72];
    const int cl = threadIdx.x >> 2, seg = threadIdx.x & 3;
    const int c = c0 + cl;
    const int g = c >> 5;
    const float mean = stats[b * 8 + g], rstd = stats[32 + b * 8 + g];
    const float scale = b2f(nw[c]) * rstd;
    const float shift = b2f(nb[c]) - mean * scale;
    const u16* xp = x + ((size_t)(b * 256 + c)) * 4096 + p0 + seg * 16;
#pragma unroll
    for (int h = 0; h < 2; h++) {
        bf16x8 v = *(const bf16x8*)(xp + h * 8);
#pragma unroll
        for (int j = 0; j < 8; j++)
            t[seg * 16 + h * 8 + j][cl] = f2b((float)v[j] * scale + shift);
    }
    __syncthreads();
    u16x8 o0, o1;
#pragma unroll
    for (int j = 0; j < 8; j++) { o0[j] = t[cl][seg * 16 + j]; o1[j] = t[cl][seg * 16 + 8 + j]; }
    u16* op = tok + ((size_t)(b * 4096 + p0 + cl)) * 256 + c0 + seg * 16;
    *(u16x8*)op = o0;
    *((u16x8*)op + 1) = o1;
}

// ---------------------------------------------------------------- QKV GEMM (swizzled LDS)
__global__ __launch_bounds__(256) void k_qkv(const u16* __restrict__ A, const u16* __restrict__ W,
                                             const u16* __restrict__ bias,
                                             u16* __restrict__ Qo, u16* __restrict__ Ko, u16* __restrict__ Vt) {
    const int m0 = blockIdx.x * 128, n0 = blockIdx.y * 128;
    const int tid = threadIdx.x, w = tid >> 6, lane = tid & 63, l15 = lane & 15, l4 = lane >> 4;
    const int wm = w >> 1, wn = w & 1;
    __shared__ __attribute__((aligned(16))) u16 At[128 * 64];
    __shared__ __attribute__((aligned(16))) u16 Bt[128 * 64];
    f32x4 acc[4][4];
    const f32x4 z = {0.f, 0.f, 0.f, 0.f};
#pragma unroll
    for (int i = 0; i < 4; i++)
#pragma unroll
        for (int j = 0; j < 4; j++) acc[i][j] = z;

    for (int kt = 0; kt < 4; kt++) {
        const int k0 = kt * 64;
#pragma unroll
        for (int i = 0; i < 4; i++) {
            int v = tid + i * 256;
            int row = v >> 3, c8 = v & 7;
            int swz = (c8 ^ (row & 7)) << 3;
            *(u16x8*)(&At[row * 64 + swz]) = *(const u16x8*)(A + (size_t)(m0 + row) * 256 + k0 + c8 * 8);
            *(u16x8*)(&Bt[row * 64 + swz]) = *(const u16x8*)(W + (size_t)(n0 + row) * 256 + k0 + c8 * 8);
        }
        __syncthreads();
#pragma unroll
        for (int ks = 0; ks < 2; ks++) {
            const int sc = ((ks * 4 + l4) ^ (l15 & 7)) << 3;
            bf16x8 af[4], bfr[4];
#pragma unroll
            for (int i = 0; i < 4; i++) {
                af[i]  = *(const bf16x8*)(&At[(wm * 64 + i * 16 + l15) * 64 + sc]);
                bfr[i] = *(const bf16x8*)(&Bt[(wn * 64 + i * 16 + l15) * 64 + sc]);
            }
#pragma unroll
            for (int i = 0; i < 4; i++)
#pragma unroll
                for (int j = 0; j < 4; j++) acc[i][j] = mfma16(af[i], bfr[j], acc[i][j]);
        }
        __syncthreads();
    }
#pragma unroll
    for (int j = 0; j < 4; j++) {
        const int n = n0 + wn * 64 + j * 16 + l15;
        const float bia = b2f(bias[n]);
#pragma unroll
        for (int i = 0; i < 4; i++) {
#pragma unroll
            for (int r = 0; r < 4; r++) {
                const int m = m0 + wm * 64 + i * 16 + l4 * 4 + r;
                const float vv = acc[i][j][r] + bia;
                if (n < 256)       Qo[(size_t)m * 256 + n] = f2b(vv);
                else if (n < 512)  Ko[(size_t)m * 256 + (n - 256)] = f2b(vv);
                else {
                    const int bb = m >> 12, p = m & 4095;
                    Vt[((size_t)bb * 256 + (n - 512)) * 4096 + p] = f2b(vv);
                }
            }
        }
    }
}

// ---------------------------------------------------------------- flash attention v2
// block = 128 threads (2 waves), each wave 32 q-rows (2 MFMA tiles); 64 q-rows/block.
// Double-buffered async DMA staging, raw barriers, swizzled LDS.
__global__ __launch_bounds__(128) void k_attn(const u16* __restrict__ Q, const u16* __restrict__ K,
                                              const u16* __restrict__ Vt, u16* __restrict__ O) {
    const int qt = blockIdx.x, b = blockIdx.y;
    const int tid = threadIdx.x, w = tid >> 6, lane = tid & 63, l15 = lane & 15, l4 = lane >> 4;
    const int srow = lane >> 2, sseg = lane & 3;
    const int qw0 = qt * 64 + w * 32;

    __shared__ __attribute__((aligned(16))) u16 KT[2][64 * 256];   // [buf][row j][col c] swizzled
    __shared__ __attribute__((aligned(16))) u16 VT[2][256 * 64];   // [buf][row c][col j] swizzled
    __shared__ __attribute__((aligned(16))) char SP[2][2][4608];   // per (wave, qtile): S f32[16][68] / P u16[16][72] aliased
    __shared__ __attribute__((aligned(16))) float aB[2][2][16];

    // Q fragments: 2 tiles x 8 kb
    bf16x8 aq[2][8];
#pragma unroll
    for (int a = 0; a < 2; a++) {
        const u16* qp = Q + ((size_t)(b * 4096 + qw0 + a * 16 + l15)) * 256 + l4 * 8;
#pragma unroll
        for (int kb = 0; kb < 8; kb++) aq[a][kb] = *(const bf16x8*)(qp + kb * 32);
    }

    // DMA per-lane global byte offsets
    int goffK[16], goffV[16];
#pragma unroll
    for (int i = 0; i < 16; i++) {
        int idx = w * 16 + i;
        int row = idx * 2 + (lane >> 5);
        int c = lane & 31;
        goffK[i] = (b * 4096 + row) * 512 + ((c ^ (row & 7)) << 4);
        int rowv = idx * 8 + (lane >> 3);
        int ch = lane & 7;
        goffV[i] = (b * 256 + rowv) * 8192 + ((ch ^ (rowv & 7)) << 4);
    }

    f32x4 acc[2][16];
    const f32x4 z = {0.f, 0.f, 0.f, 0.f};
#pragma unroll
    for (int a = 0; a < 2; a++)
#pragma unroll
        for (int i = 0; i < 16; i++) acc[a][i] = z;
    float m_i[2] = {-1e30f, -1e30f};    // per-lane row = srow of tile a
    float l_i[2] = {0.f, 0.f};

    const char* Kc = (const char*)K;
    const char* Vc = (const char*)Vt;

    // prologue: stage tile 0 into buf 0
#pragma unroll
    for (int i = 0; i < 16; i++) dma16(Kc + goffK[i], (char*)&KT[0][0] + (w * 16 + i) * 1024);
#pragma unroll
    for (int i = 0; i < 16; i++) dma16(Vc + goffV[i], (char*)&VT[0][0] + (w * 16 + i) * 1024);

    char* SP0 = SP[w][0];
    char* SP1 = SP[w][1];

    for (int kt = 0; kt < 64; kt++) {
        const int cur = kt & 1;
        if (kt < 63) {
            const int nxt = cur ^ 1;
            const int okk = (kt + 1) * 32768, okv = (kt + 1) * 128;
#pragma unroll
            for (int i = 0; i < 16; i++) dma16(Kc + (goffK[i] + okk), (char*)&KT[nxt][0] + (w * 16 + i) * 1024);
#pragma unroll
            for (int i = 0; i < 16; i++) dma16(Vc + (goffV[i] + okv), (char*)&VT[nxt][0] + (w * 16 + i) * 1024);
            asm volatile("s_waitcnt vmcnt(32)" ::: "memory");
        } else {
            asm volatile("s_waitcnt vmcnt(0)" ::: "memory");
        }
        asm volatile("s_barrier" ::: "memory");

        // ---- S = Q K^T (both q-tiles share B-fragments)
        const u16* KTc = &KT[cur][0];
        f32x4 s0[4], s1[4];
#pragma unroll
        for (int nt = 0; nt < 4; nt++) { s0[nt] = z; s1[nt] = z; }
#pragma unroll
        for (int kb = 0; kb < 8; kb++) {
#pragma unroll
            for (int nt = 0; nt < 4; nt++) {
                const int row = nt * 16 + l15;
                bf16x8 bk = *(const bf16x8*)(&KTc[row * 256 + (((kb * 4 + l4) ^ (l15 & 7)) << 3)]);
                s0[nt] = mfma16(aq[0][kb], bk, s0[nt]);
                s1[nt] = mfma16(aq[1][kb], bk, s1[nt]);
            }
        }
        // write S (C-layout) to per-wave scratch, f32 rows of 68
        {
            float* p0 = (float*)SP0;
            float* p1 = (float*)SP1;
#pragma unroll
            for (int nt = 0; nt < 4; nt++)
#pragma unroll
                for (int r = 0; r < 4; r++) {
                    p0[(l4 * 4 + r) * 68 + nt * 16 + l15] = s0[nt][r] * 0.0625f;
                    p1[(l4 * 4 + r) * 68 + nt * 16 + l15] = s1[nt][r] * 0.0625f;
                }
        }
        asm volatile("s_waitcnt lgkmcnt(0)" ::: "memory");

        // ---- online softmax per tile (rows across 4 lanes)
#pragma unroll
        for (int a = 0; a < 2; a++) {
            char* sp = a ? SP1 : SP0;
            float px[16];
#pragma unroll
            for (int q = 0; q < 4; q++) {
                f32x4 v = *(const f32x4*)(sp + srow * 272 + sseg * 64 + q * 16);
#pragma unroll
                for (int r = 0; r < 4; r++) px[q * 4 + r] = v[r];
            }
            float mx = px[0];
#pragma unroll
            for (int j = 1; j < 16; j++) mx = fmaxf(mx, px[j]);
            mx = fmaxf(mx, __shfl_xor(mx, 1, 64));
            mx = fmaxf(mx, __shfl_xor(mx, 2, 64));
            const float m_new = fmaxf(m_i[a], mx);
            const float alpha = __expf(fminf(m_i[a] - m_new, 0.f));
            m_i[a] = m_new;
            float sum = 0.f;
            u16x8 pk0, pk1;
#pragma unroll
            for (int j = 0; j < 8; j++) {
                float e = __expf(fminf(px[j] - m_new, 0.f));
                sum += e; pk0[j] = f2b(e);
            }
#pragma unroll
            for (int j = 0; j < 8; j++) {
                float e = __expf(fminf(px[8 + j] - m_new, 0.f));
                sum += e; pk1[j] = f2b(e);
            }
            sum += __shfl_xor(sum, 1, 64);
            sum += __shfl_xor(sum, 2, 64);
            l_i[a] = l_i[a] * alpha + sum;
            // P row-major u16 [16][72], aliases S region (S fully consumed)
            *(u16x8*)(sp + srow * 144 + sseg * 32) = pk0;
            *(u16x8*)(sp + srow * 144 + sseg * 32 + 16) = pk1;
            if (sseg == 0) aB[w][a][srow] = alpha;
        }
        asm volatile("s_waitcnt lgkmcnt(0)" ::: "memory");

        // ---- rescale acc, then acc += P V
#pragma unroll
        for (int a = 0; a < 2; a++) {
            f32x4 ar = *(const f32x4*)&aB[w][a][l4 * 4];
#pragma unroll
            for (int nt = 0; nt < 16; nt++)
#pragma unroll
                for (int r = 0; r < 4; r++) acc[a][nt][r] *= ar[r];
        }
        const u16* VTc = &VT[cur][0];
#pragma unroll
        for (int ks = 0; ks < 2; ks++) {
            bf16x8 ap0 = *(const bf16x8*)(SP0 + l15 * 144 + ks * 64 + l4 * 16);
            bf16x8 ap1 = *(const bf16x8*)(SP1 + l15 * 144 + ks * 64 + l4 * 16);
#pragma unroll
            for (int nt = 0; nt < 16; nt++) {
                const int row = nt * 16 + l15;
                bf16x8 bv = *(const bf16x8*)(&VTc[row * 64 + (((ks * 4 + l4) ^ (l15 & 7)) << 3)]);
                acc[0][nt] = mfma16(ap0, bv, acc[0][nt]);
                acc[1][nt] = mfma16(ap1, bv, acc[1][nt]);
            }
        }
        asm volatile("s_barrier" ::: "memory");   // protect cur before next overwrite
    }

    // epilogue: 1/l via aB round-trip
    if (sseg == 0) { aB[w][0][srow] = l_i[0]; aB[w][1][srow] = l_i[1]; }
    asm volatile("s_waitcnt lgkmcnt(0)" ::: "memory");
#pragma unroll
    for (int a = 0; a < 2; a++) {
        f32x4 lv = *(const f32x4*)&aB[w][a][l4 * 4];
        f32x4 invl;
#pragma unroll
        for (int r = 0; r < 4; r++) invl[r] = 1.0f / fmaxf(lv[r], 1e-30f);
#pragma unroll
        for (int nt = 0; nt < 16; nt++) {
            const int col = nt * 16 + l15;
#pragma unroll
            for (int r = 0; r < 4; r++) {
                const int rowg = qw0 + a * 16 + l4 * 4 + r;
                O[((size_t)(b * 4096 + rowg)) * 256 + col] = f2b(acc[a][nt][r] * invl[r]);
            }
        }
    }
}

// ---------------------------------------------------------------- proj GEMM + residual, store [b][c][p]
__global__ __launch_bounds__(256) void k_proj(const u16* __restrict__ A, const u16* __restrict__ W,
                                              const u16* __restrict__ bias, const u16* __restrict__ x,
                                              void* __restrict__ out, const int* __restrict__ flag) {
    const int f32out = *flag;
    const int m0 = blockIdx.x * 128, n0 = blockIdx.y * 128;
    const int tid = threadIdx.x, w = tid >> 6, lane = tid & 63, l15 = lane & 15, l4 = lane >> 4;
    const int wm = w >> 1, wn = w & 1;
    __shared__ __attribute__((aligned(16))) u16 At[128 * 64];
    __shared__ __attribute__((aligned(16))) u16 Bt[128 * 64];
    f32x4 acc[4][4];
    const f32x4 z = {0.f, 0.f, 0.f, 0.f};
#pragma unroll
    for (int i = 0; i < 4; i++)
#pragma unroll
        for (int j = 0; j < 4; j++) acc[i][j] = z;

    for (int kt = 0; kt < 4; kt++) {
        const int k0 = kt * 64;
#pragma unroll
        for (int i = 0; i < 4; i++) {
            int v = tid + i * 256;
            int row = v >> 3, c8 = v & 7;
            int swz = (c8 ^ (row & 7)) << 3;
            *(u16x8*)(&At[row * 64 + swz]) = *(const u16x8*)(A + (size_t)(m0 + row) * 256 + k0 + c8 * 8);
            *(u16x8*)(&Bt[row * 64 + swz]) = *(const u16x8*)(W + (size_t)(n0 + row) * 256 + k0 + c8 * 8);
        }
        __syncthreads();
#pragma unroll
        for (int ks = 0; ks < 2; ks++) {
            const int sc = ((ks * 4 + l4) ^ (l15 & 7)) << 3;
            bf16x8 af[4], bfr[4];
#pragma unroll
            for (int i = 0; i < 4; i++) {
                af[i]  = *(const bf16x8*)(&At[(wm * 64 + i * 16 + l15) * 64 + sc]);
                bfr[i] = *(const bf16x8*)(&Bt[(wn * 64 + i * 16 + l15) * 64 + sc]);
            }
#pragma unroll
            for (int i = 0; i < 4; i++)
#pragma unroll
                for (int j = 0; j < 4; j++) acc[i][j] = mfma16(af[i], bfr[j], acc[i][j]);
        }
        __syncthreads();
    }
#pragma unroll
    for (int j = 0; j < 4; j++) {
        const int n = n0 + wn * 64 + j * 16 + l15;
        const float bia = b2f(bias[n]);
#pragma unroll
        for (int i = 0; i < 4; i++) {
#pragma unroll
            for (int r = 0; r < 4; r++) {
                const int m = m0 + wm * 64 + i * 16 + l4 * 4 + r;
                const int bb = m >> 12, p = m & 4095;
                const size_t oi = ((size_t)bb * 256 + n) * 4096 + p;
                const float v = b2f(x[oi]) + acc[i][j][r] + bia;
                if (f32out) ((float*)out)[oi] = v;
                else        ((u16*)out)[oi] = f2b(v);
            }
        }
    }
}

extern "C" void kernel_launch(void* const* d_in, const int* in_sizes, int n_in,
                              void* d_out, int out_size, void* d_ws, size_t ws_size,
                              hipStream_t stream) {
    char* ws = (char*)d_ws;
    float* stats = (float*)ws;                                   // 256 B
    int*   flag  = (int*)(ws + 2048);
    u16* xb  = (u16*)(ws + 4096);                                // 4194304 u16
    u16* nwb = xb + (size_t)4194304;                             // 256
    u16* nbb = nwb + 256;                                        // 256
    u16* qbb = nbb + 256;                                        // 768
    u16* pbb = qbb + 768;                                        // 256
    u16* pad = pbb + 256;
    u16* qwb = pad + 256;                                        // 196608
    u16* pwb = qwb + (size_t)196608;                             // 65536
    u16* tok = pwb + (size_t)65536;                              // [16384][256], reused as Ob
    u16* Qb  = tok + (size_t)16384 * 256;
    u16* Kb  = Qb  + (size_t)16384 * 256;
    u16* Vb  = Kb  + (size_t)16384 * 256;                        // [4][256][4096]
    u16* Ob  = tok;

    k_detect<<<dim3(1), dim3(256), 0, stream>>>((const unsigned*)d_in[0], flag);
    k_cvtx<<<dim3(4096), dim3(256), 0, stream>>>(d_in[0], xb, flag);
    k_cvtp<<<dim3(1030), dim3(256), 0, stream>>>(d_in[1], d_in[2], d_in[3], d_in[4], d_in[5], d_in[6],
                                                 nwb, nbb, qwb, qbb, pwb, pbb, flag);

    k_stats<<<dim3(32), dim3(256), 0, stream>>>(xb, stats);
    k_tok  <<<dim3(64, 4, 4), dim3(256), 0, stream>>>(xb, nwb, nbb, stats, tok);
    k_qkv  <<<dim3(128, 6), dim3(256), 0, stream>>>(tok, qwb, qbb, Qb, Kb, Vb);
    k_attn <<<dim3(64, 4), dim3(128), 0, stream>>>(Qb, Kb, Vb, Ob);
    k_proj <<<dim3(128, 2), dim3(256), 0, stream>>>(Ob, pwb, pbb, xb, d_out, flag);
}

// Round 4
// 335.027 us; speedup vs baseline: 1.3885x; 1.2539x over previous
//
#include <hip/hip_runtime.h>
#include <math.h>

typedef unsigned short u16;
typedef __bf16 bf16x8 __attribute__((ext_vector_type(8)));
typedef u16    u16x8  __attribute__((ext_vector_type(8)));
typedef u16    u16x4  __attribute__((ext_vector_type(4)));
typedef float  f32x4  __attribute__((ext_vector_type(4)));
typedef float  f32x16 __attribute__((ext_vector_type(16)));

__device__ __forceinline__ float b2f(u16 u) {
    union { unsigned u; float f; } x; x.u = ((unsigned)u) << 16; return x.f;
}
__device__ __forceinline__ u16 f2b(float f) {
    union { float f; unsigned u; } x; x.f = f;
    unsigned r = x.u + 0x7FFFu + ((x.u >> 16) & 1u);   // RNE
    return (u16)(r >> 16);
}
__device__ __forceinline__ f32x4 mfma16(bf16x8 a, bf16x8 b, f32x4 c) {
    return __builtin_amdgcn_mfma_f32_16x16x32_bf16(a, b, c, 0, 0, 0);
}
__device__ __forceinline__ f32x16 mfma32(bf16x8 a, bf16x8 b, f32x16 c) {
    return __builtin_amdgcn_mfma_f32_32x32x16_bf16(a, b, c, 0, 0, 0);
}
__device__ __forceinline__ void dma16(const void* g, void* l) {
    __builtin_amdgcn_global_load_lds((const __attribute__((address_space(1))) void*)g,
                                     (__attribute__((address_space(3))) void*)l, 16, 0, 0);
}

// ---------------------------------------------------------------- dtype detector
__global__ __launch_bounds__(256) void k_detect(const unsigned* __restrict__ x32, int* __restrict__ flag) {
    __shared__ int cnt;
    if (threadIdx.x == 0) cnt = 0;
    __syncthreads();
    int local = 0;
    for (int i = threadIdx.x; i < 4096; i += 256) {
        unsigned lo = x32[i] & 0xFFFFu;
        unsigned e = (lo >> 7) & 0xFFu;
        if (e >= 0x60u && e <= 0x8Fu) local++;
    }
    atomicAdd(&cnt, local);
    __syncthreads();
    if (threadIdx.x == 0) *flag = (cnt >= 2048) ? 0 : 1;
}

// ---------------------------------------------------------------- x convert
__global__ __launch_bounds__(256) void k_cvtx(const void* __restrict__ src, u16* __restrict__ dst,
                                              const int* __restrict__ flag) {
    const int i = (blockIdx.x * 256 + threadIdx.x) * 4;
    if (*flag) {
        float4 v = *(const float4*)((const float*)src + i);
        u16 o0 = f2b(v.x), o1 = f2b(v.y), o2 = f2b(v.z), o3 = f2b(v.w);
        unsigned lo = (unsigned)o0 | ((unsigned)o1 << 16);
        unsigned hi = (unsigned)o2 | ((unsigned)o3 << 16);
        *(uint2*)(dst + i) = make_uint2(lo, hi);
    } else {
        *(uint2*)(dst + i) = *(const uint2*)((const u16*)src + i);
    }
}

// ---------------------------------------------------------------- params convert
__global__ __launch_bounds__(256) void k_cvtp(const void* s0, const void* s1, const void* s2,
                                              const void* s3, const void* s4, const void* s5,
                                              u16* d0, u16* d1, u16* d2, u16* d3, u16* d4, u16* d5,
                                              const int* __restrict__ flag) {
    const int i = blockIdx.x * 256 + threadIdx.x;
    const int f = *flag;
    const void* s; u16* d; int j;
    if      (i < 256)    { s = s0; d = d0; j = i; }
    else if (i < 512)    { s = s1; d = d1; j = i - 256; }
    else if (i < 197120) { s = s2; d = d2; j = i - 512; }
    else if (i < 197888) { s = s3; d = d3; j = i - 197120; }
    else if (i < 263424) { s = s4; d = d4; j = i - 197888; }
    else if (i < 263680) { s = s5; d = d5; j = i - 263424; }
    else return;
    if (f) d[j] = f2b(((const float*)s)[j]);
    else   d[j] = ((const u16*)s)[j];
}

// ---------------------------------------------------------------- group-norm stats
__global__ __launch_bounds__(256) void k_stats(const u16* __restrict__ x, float* __restrict__ stats) {
    const int bg = blockIdx.x;
    const u16* p = x + (size_t)bg * 131072;
    float s = 0.f, ss = 0.f;
    for (int i = threadIdx.x; i < 16384; i += 256) {
        bf16x8 v = *(const bf16x8*)(p + i * 8);
#pragma unroll
        for (int j = 0; j < 8; j++) { float f = (float)v[j]; s += f; ss += f * f; }
    }
#pragma unroll
    for (int o = 1; o < 64; o <<= 1) { s += __shfl_xor(s, o, 64); ss += __shfl_xor(ss, o, 64); }
    __shared__ float rs[4], rss[4];
    const int wv = threadIdx.x >> 6;
    if ((threadIdx.x & 63) == 0) { rs[wv] = s; rss[wv] = ss; }
    __syncthreads();
    if (threadIdx.x == 0) {
        s = rs[0] + rs[1] + rs[2] + rs[3];
        ss = rss[0] + rss[1] + rss[2] + rss[3];
        float mean = s * (1.f / 131072.f);
        float var = fmaxf(ss * (1.f / 131072.f) - mean * mean, 0.f);
        stats[bg] = mean;
        stats[32 + bg] = rsqrtf(var + 1e-5f);
    }
}

// ---------------------------------------------------------------- normalize + transpose to tokens [b][n][c]
__global__ __launch_bounds__(256) void k_tok(const u16* __restrict__ x, const u16* __restrict__ nw,
                                             const u16* __restrict__ nb, const float* __restrict__ stats,
                                             u16* __restrict__ tok) {
    const int b = blockIdx.z, c0 = blockIdx.y * 64, p0 = blockIdx.x * 64;
    __shared__ u16 t[64][72];
    const int cl = threadIdx.x >> 2, seg = threadIdx.x & 3;
    const int c = c0 + cl;
    const int g = c >> 5;
    const float mean = stats[b * 8 + g], rstd = stats[32 + b * 8 + g];
    const float scale = b2f(nw[c]) * rstd;
    const float shift = b2f(nb[c]) - mean * scale;
    const u16* xp = x + ((size_t)(b * 256 + c)) * 4096 + p0 + seg * 16;
#pragma unroll
    for (int h = 0; h < 2; h++) {
        bf16x8 v = *(const bf16x8*)(xp + h * 8);
#pragma unroll
        for (int j = 0; j < 8; j++)
            t[seg * 16 + h * 8 + j][cl] = f2b((float)v[j] * scale + shift);
    }
    __syncthreads();
    u16x8 o0, o1;
#pragma unroll
    for (int j = 0; j < 8; j++) { o0[j] = t[cl][seg * 16 + j]; o1[j] = t[cl][seg * 16 + 8 + j]; }
    u16* op = tok + ((size_t)(b * 4096 + p0 + cl)) * 256 + c0 + seg * 16;
    *(u16x8*)op = o0;
    *((u16x8*)op + 1) = o1;
}

// ---------------------------------------------------------------- QKV GEMM (swizzled LDS)
__global__ __launch_bounds__(256) void k_qkv(const u16* __restrict__ A, const u16* __restrict__ W,
                                             const u16* __restrict__ bias,
                                             u16* __restrict__ Qo, u16* __restrict__ Ko, u16* __restrict__ Vt) {
    const int m0 = blockIdx.x * 128, n0 = blockIdx.y * 128;
    const int tid = threadIdx.x, w = tid >> 6, lane = tid & 63, l15 = lane & 15, l4 = lane >> 4;
    const int wm = w >> 1, wn = w & 1;
    __shared__ __attribute__((aligned(16))) u16 At[128 * 64];
    __shared__ __attribute__((aligned(16))) u16 Bt[128 * 64];
    f32x4 acc[4][4];
    const f32x4 z = {0.f, 0.f, 0.f, 0.f};
#pragma unroll
    for (int i = 0; i < 4; i++)
#pragma unroll
        for (int j = 0; j < 4; j++) acc[i][j] = z;

    for (int kt = 0; kt < 4; kt++) {
        const int k0 = kt * 64;
#pragma unroll
        for (int i = 0; i < 4; i++) {
            int v = tid + i * 256;
            int row = v >> 3, c8 = v & 7;
            int swz = (c8 ^ (row & 7)) << 3;
            *(u16x8*)(&At[row * 64 + swz]) = *(const u16x8*)(A + (size_t)(m0 + row) * 256 + k0 + c8 * 8);
            *(u16x8*)(&Bt[row * 64 + swz]) = *(const u16x8*)(W + (size_t)(n0 + row) * 256 + k0 + c8 * 8);
        }
        __syncthreads();
#pragma unroll
        for (int ks = 0; ks < 2; ks++) {
            const int sc = ((ks * 4 + l4) ^ (l15 & 7)) << 3;
            bf16x8 af[4], bfr[4];
#pragma unroll
            for (int i = 0; i < 4; i++) {
                af[i]  = *(const bf16x8*)(&At[(wm * 64 + i * 16 + l15) * 64 + sc]);
                bfr[i] = *(const bf16x8*)(&Bt[(wn * 64 + i * 16 + l15) * 64 + sc]);
            }
#pragma unroll
            for (int i = 0; i < 4; i++)
#pragma unroll
                for (int j = 0; j < 4; j++) acc[i][j] = mfma16(af[i], bfr[j], acc[i][j]);
        }
        __syncthreads();
    }
#pragma unroll
    for (int j = 0; j < 4; j++) {
        const int n = n0 + wn * 64 + j * 16 + l15;
        const float bia = b2f(bias[n]);
#pragma unroll
        for (int i = 0; i < 4; i++) {
#pragma unroll
            for (int r = 0; r < 4; r++) {
                const int m = m0 + wm * 64 + i * 16 + l4 * 4 + r;
                const float vv = acc[i][j][r] + bia;
                if (n < 256)       Qo[(size_t)m * 256 + n] = f2b(vv);
                else if (n < 512)  Ko[(size_t)m * 256 + (n - 256)] = f2b(vv);
                else {
                    const int bb = m >> 12, p = m & 4095;
                    Vt[((size_t)bb * 256 + (n - 512)) * 4096 + p] = f2b(vv);
                }
            }
        }
    }
}

// ---------------------------------------------------------------- flash attention v3: 32x32 MFMA + k-split
// grid (64 qtiles, 4 b, 4 splits); block 128 = 2 waves x 32 q-rows; Bc=32; 32 iters/block.
// Outputs UNNORMALIZED partial O (bf16, [split][b][c][q]) + (m,l) per row.
__global__ __launch_bounds__(128) void k_attn(const u16* __restrict__ Q, const u16* __restrict__ K,
                                              const u16* __restrict__ Vt,
                                              u16* __restrict__ Up, float* __restrict__ ml) {
    const int qt = blockIdx.x, b = blockIdx.y, sp = blockIdx.z;
    const int tid = threadIdx.x, w = tid >> 6, lane = tid & 63;
    const int l31 = lane & 31, h = lane >> 5;

    __shared__ __attribute__((aligned(16))) u16 KT[32 * 256];   // [j][k], 16B-chunk ^ j swizzle
    __shared__ __attribute__((aligned(16))) u16 VT[256 * 32];   // [c][j], 16B-chunk ^ (c>>3)&3 swizzle
    __shared__ __attribute__((aligned(16))) float Sb[2][32 * 36];
    __shared__ __attribute__((aligned(16))) u16  Pb[2][32 * 40];
    __shared__ float aB[2][32];

    // Q A-fragments: row = l31, k = kb*16 + h*8 + j
    bf16x8 aq[16];
    {
        const u16* qp = Q + ((size_t)(b * 4096 + qt * 64 + w * 32 + l31)) * 256 + h * 8;
#pragma unroll
        for (int kb = 0; kb < 16; kb++) aq[kb] = *(const bf16x8*)(qp + kb * 16);
    }
    f32x16 acc[8];
#pragma unroll
    for (int ct = 0; ct < 8; ct++)
#pragma unroll
        for (int r = 0; r < 16; r++) acc[ct][r] = 0.f;
    float m_i = -1e30f, l_i = 0.f;     // owned by lane-pair: row = lane>>1

    const int srow = lane >> 1, sseg = lane & 1;
    float* sw = &Sb[w][0];
    u16*  pw = &Pb[w][0];

    for (int kt = 0; kt < 32; kt++) {
        const int j0 = sp * 1024 + kt * 32;
        // ---- stage K tile (16 KB) + V tile (16 KB), swizzle on GLOBAL side
        {
            const u16* Kg = K + (size_t)(b * 4096 + j0) * 256;
#pragma unroll
            for (int i = 0; i < 4; i++) {
                int q = i * 128 + tid;
                int row = q >> 5, c = q & 31;
                dma16(Kg + row * 256 + ((c ^ row) << 3), &KT[(i * 128 + (tid & 64)) * 8]);
            }
            const u16* Vg = Vt + (size_t)b * 256 * 4096 + j0;
#pragma unroll
            for (int i = 0; i < 2; i++) {
                int q = i * 128 + tid;
                int row = q >> 2, c = q & 3;
                dma16(Vg + (size_t)row * 4096 + ((c ^ ((row >> 3) & 3)) << 3), &VT[(i * 128 + (tid & 64)) * 8]);
            }
#pragma unroll
            for (int i = 4; i < 8; i++) {
                int q = i * 128 + tid;
                int row = q >> 5, c = q & 31;
                dma16(Kg + row * 256 + ((c ^ row) << 3), &KT[(i * 128 + (tid & 64)) * 8]);
            }
#pragma unroll
            for (int i = 2; i < 8; i++) {
                int q = i * 128 + tid;
                int row = q >> 2, c = q & 3;
                dma16(Vg + (size_t)row * 4096 + ((c ^ ((row >> 3) & 3)) << 3), &VT[(i * 128 + (tid & 64)) * 8]);
            }
        }
        asm volatile("s_waitcnt vmcnt(0)" ::: "memory");
        __syncthreads();

        // ---- S = Q K^T : 16 mfma32, B-frag col j = l31
        f32x16 s;
#pragma unroll
        for (int r = 0; r < 16; r++) s[r] = 0.f;
#pragma unroll
        for (int kb = 0; kb < 16; kb++) {
            bf16x8 bk = *(const bf16x8*)(&KT[l31 * 256 + (((kb * 2 + h) ^ l31) << 3)]);
            s = mfma32(aq[kb], bk, s);
        }
        // write S scaled to base-2 domain; C-layout row = (r&3)+8*(r>>2)+4*h, col = l31
#pragma unroll
        for (int r = 0; r < 16; r++)
            sw[((r & 3) + 8 * (r >> 2) + 4 * h) * 36 + l31] = s[r] * 0.090168924f; // 1/16 * log2(e)
        asm volatile("s_waitcnt lgkmcnt(0)" ::: "memory");

        // ---- online softmax: lane pair owns row = lane>>1, halves by sseg
        float px[16];
#pragma unroll
        for (int qq = 0; qq < 4; qq++) {
            f32x4 v = *(const f32x4*)(&sw[srow * 36 + sseg * 16 + qq * 4]);
#pragma unroll
            for (int r = 0; r < 4; r++) px[qq * 4 + r] = v[r];
        }
        float mx = px[0];
#pragma unroll
        for (int j = 1; j < 16; j++) mx = fmaxf(mx, px[j]);
        mx = fmaxf(mx, __shfl_xor(mx, 1, 64));
        const float m_new = fmaxf(m_i, mx);
        const float alpha = __builtin_amdgcn_exp2f(m_i - m_new);
        float sum = 0.f;
        u16x8 p0, p1;
#pragma unroll
        for (int j = 0; j < 8; j++) {
            float e = __builtin_amdgcn_exp2f(px[j] - m_new);
            sum += e; p0[j] = f2b(e);
        }
#pragma unroll
        for (int j = 0; j < 8; j++) {
            float e = __builtin_amdgcn_exp2f(px[8 + j] - m_new);
            sum += e; p1[j] = f2b(e);
        }
        sum += __shfl_xor(sum, 1, 64);
        l_i = l_i * alpha + sum;
        m_i = m_new;
        *(u16x8*)(&pw[srow * 40 + sseg * 16]) = p0;
        *(u16x8*)(&pw[srow * 40 + sseg * 16 + 8]) = p1;
        if (sseg == 0) aB[w][srow] = alpha;
        asm volatile("s_waitcnt lgkmcnt(0)" ::: "memory");

        // ---- rescale acc then acc += P V
#pragma unroll
        for (int r = 0; r < 16; r++) {
            const float al = aB[w][(r & 3) + 8 * (r >> 2) + 4 * h];
#pragma unroll
            for (int ct = 0; ct < 8; ct++) acc[ct][r] *= al;
        }
#pragma unroll
        for (int kf = 0; kf < 2; kf++) {
            bf16x8 ap = *(const bf16x8*)(&pw[l31 * 40 + kf * 16 + h * 8]);
#pragma unroll
            for (int ct = 0; ct < 8; ct++) {
                bf16x8 bv = *(const bf16x8*)(&VT[(ct * 32 + l31) * 32 + (((kf * 2 + h) ^ (l31 >> 3)) << 3)]);
                acc[ct] = mfma32(ap, bv, acc[ct]);
            }
        }
        __syncthreads();
    }

    // ---- epilogue: write (m,l) and unnormalized partial O (bf16, [c][q])
    if (sseg == 0)
        ((float2*)ml)[(size_t)(sp * 4 + b) * 4096 + qt * 64 + w * 32 + srow] = make_float2(m_i, l_i);
#pragma unroll
    for (int ct = 0; ct < 8; ct++) {
#pragma unroll
        for (int rq = 0; rq < 4; rq++) {
            u16x4 o;
#pragma unroll
            for (int rr = 0; rr < 4; rr++) o[rr] = f2b(acc[ct][rq * 4 + rr]);
            *(u16x4*)(Up + (size_t)((sp * 4 + b) * 256 + ct * 32 + l31) * 4096
                         + qt * 64 + w * 32 + rq * 8 + h * 4) = o;
        }
    }
}

// ---------------------------------------------------------------- combine k-splits -> Ob [q][c] bf16
__global__ __launch_bounds__(256) void k_comb(const u16* __restrict__ Up, const float* __restrict__ ml,
                                              u16* __restrict__ Ob) {
    const int qt = blockIdx.x, b = blockIdx.y;
    const int tid = threadIdx.x, ql = tid & 63, cg = tid >> 6;
    const int q = qt * 64 + ql;
    __shared__ __attribute__((aligned(16))) u16 T[64 * 256];   // [q][c], chunk ^ (q&31) swizzle
    float w_s[4];
    {
        float m_s[4], l_s[4];
#pragma unroll
        for (int s = 0; s < 4; s++) {
            float2 v = ((const float2*)ml)[(size_t)(s * 4 + b) * 4096 + q];
            m_s[s] = v.x; l_s[s] = v.y;
        }
        float M = fmaxf(fmaxf(m_s[0], m_s[1]), fmaxf(m_s[2], m_s[3]));
        float L = 0.f, e[4];
#pragma unroll
        for (int s = 0; s < 4; s++) { e[s] = __builtin_amdgcn_exp2f(m_s[s] - M); L += l_s[s] * e[s]; }
        float inv = 1.f / fmaxf(L, 1e-30f);
#pragma unroll
        for (int s = 0; s < 4; s++) w_s[s] = e[s] * inv;
    }
#pragma unroll
    for (int j8 = 0; j8 < 8; j8++) {
        u16x8 o;
#pragma unroll
        for (int e = 0; e < 8; e++) {
            const int c = cg * 64 + j8 * 8 + e;
            float v = 0.f;
#pragma unroll
            for (int s = 0; s < 4; s++)
                v += b2f(Up[(size_t)((s * 4 + b) * 256 + c) * 4096 + q]) * w_s[s];
            o[e] = f2b(v);
        }
        *(u16x8*)(&T[ql * 256 + (((cg * 8 + j8) ^ (ql & 31)) << 3)]) = o;
    }
    __syncthreads();
    const int ql2 = tid >> 2, cs = tid & 3;
#pragma unroll
    for (int k = 0; k < 8; k++) {
        u16x8 v = *(const u16x8*)(&T[ql2 * 256 + (((cs * 8 + k) ^ (ql2 & 31)) << 3)]);
        *(u16x8*)(Ob + (size_t)(b * 4096 + qt * 64 + ql2) * 256 + cs * 64 + k * 8) = v;
    }
}

// ---------------------------------------------------------------- proj GEMM + residual, store [b][c][p]
__global__ __launch_bounds__(256) void k_proj(const u16* __restrict__ A, const u16* __restrict__ W,
                                              const u16* __restrict__ bias, const u16* __restrict__ x,
                                              void* __restrict__ out, const int* __restrict__ flag) {
    const int f32out = *flag;
    const int m0 = blockIdx.x * 128, n0 = blockIdx.y * 128;
    const int tid = threadIdx.x, w = tid >> 6, lane = tid & 63, l15 = lane & 15, l4 = lane >> 4;
    const int wm = w >> 1, wn = w & 1;
    __shared__ __attribute__((aligned(16))) u16 At[128 * 64];
    __shared__ __attribute__((aligned(16))) u16 Bt[128 * 64];
    f32x4 acc[4][4];
    const f32x4 z = {0.f, 0.f, 0.f, 0.f};
#pragma unroll
    for (int i = 0; i < 4; i++)
#pragma unroll
        for (int j = 0; j < 4; j++) acc[i][j] = z;

    for (int kt = 0; kt < 4; kt++) {
        const int k0 = kt * 64;
#pragma unroll
        for (int i = 0; i < 4; i++) {
            int v = tid + i * 256;
            int row = v >> 3, c8 = v & 7;
            int swz = (c8 ^ (row & 7)) << 3;
            *(u16x8*)(&At[row * 64 + swz]) = *(const u16x8*)(A + (size_t)(m0 + row) * 256 + k0 + c8 * 8);
            *(u16x8*)(&Bt[row * 64 + swz]) = *(const u16x8*)(W + (size_t)(n0 + row) * 256 + k0 + c8 * 8);
        }
        __syncthreads();
#pragma unroll
        for (int ks = 0; ks < 2; ks++) {
            const int sc = ((ks * 4 + l4) ^ (l15 & 7)) << 3;
            bf16x8 af[4], bfr[4];
#pragma unroll
            for (int i = 0; i < 4; i++) {
                af[i]  = *(const bf16x8*)(&At[(wm * 64 + i * 16 + l15) * 64 + sc]);
                bfr[i] = *(const bf16x8*)(&Bt[(wn * 64 + i * 16 + l15) * 64 + sc]);
            }
#pragma unroll
            for (int i = 0; i < 4; i++)
#pragma unroll
                for (int j = 0; j < 4; j++) acc[i][j] = mfma16(af[i], bfr[j], acc[i][j]);
        }
        __syncthreads();
    }
#pragma unroll
    for (int j = 0; j < 4; j++) {
        const int n = n0 + wn * 64 + j * 16 + l15;
        const float bia = b2f(bias[n]);
#pragma unroll
        for (int i = 0; i < 4; i++) {
#pragma unroll
            for (int r = 0; r < 4; r++) {
                const int m = m0 + wm * 64 + i * 16 + l4 * 4 + r;
                const int bb = m >> 12, p = m & 4095;
                const size_t oi = ((size_t)bb * 256 + n) * 4096 + p;
                const float v = b2f(x[oi]) + acc[i][j][r] + bia;
                if (f32out) ((float*)out)[oi] = v;
                else        ((u16*)out)[oi] = f2b(v);
            }
        }
    }
}

extern "C" void kernel_launch(void* const* d_in, const int* in_sizes, int n_in,
                              void* d_out, int out_size, void* d_ws, size_t ws_size,
                              hipStream_t stream) {
    char* ws = (char*)d_ws;
    float* stats = (float*)ws;                                   // 256 B
    int*   flag  = (int*)(ws + 2048);
    u16* xb  = (u16*)(ws + 4096);                                // 4194304 u16
    u16* nwb = xb + (size_t)4194304;
    u16* nbb = nwb + 256;
    u16* qbb = nbb + 256;
    u16* pbb = qbb + 768;
    u16* pad = pbb + 256;
    u16* qwb = pad + 256;                                        // 196608
    u16* pwb = qwb + (size_t)196608;                             // 65536
    u16* tok = pwb + (size_t)65536;                              // [16384][256], reused as Ob
    u16* Qb  = tok + (size_t)16384 * 256;
    u16* Kb  = Qb  + (size_t)16384 * 256;
    u16* Vb  = Kb  + (size_t)16384 * 256;                        // [4][256][4096]
    u16* Upb = Vb  + (size_t)16384 * 256;                        // [4][4][256][4096] bf16 partials
    float* mlb = (float*)(Upb + (size_t)4 * 4 * 256 * 4096);     // [4][4][4096] float2
    u16* Ob  = tok;

    k_detect<<<dim3(1), dim3(256), 0, stream>>>((const unsigned*)d_in[0], flag);
    k_cvtx<<<dim3(4096), dim3(256), 0, stream>>>(d_in[0], xb, flag);
    k_cvtp<<<dim3(1030), dim3(256), 0, stream>>>(d_in[1], d_in[2], d_in[3], d_in[4], d_in[5], d_in[6],
                                                 nwb, nbb, qwb, qbb, pwb, pbb, flag);

    k_stats<<<dim3(32), dim3(256), 0, stream>>>(xb, stats);
    k_tok  <<<dim3(64, 4, 4), dim3(256), 0, stream>>>(xb, nwb, nbb, stats, tok);
    k_qkv  <<<dim3(128, 6), dim3(256), 0, stream>>>(tok, qwb, qbb, Qb, Kb, Vb);
    k_attn <<<dim3(64, 4, 4), dim3(128), 0, stream>>>(Qb, Kb, Vb, Upb, mlb);
    k_comb <<<dim3(64, 4), dim3(256), 0, stream>>>(Upb, mlb, Ob);
    k_proj <<<dim3(128, 2), dim3(256), 0, stream>>>(Ob, pwb, pbb, xb, d_out, flag);
}

// Round 5
// 238.147 us; speedup vs baseline: 1.9534x; 1.4068x over previous
//
#include <hip/hip_runtime.h>
#include <math.h>

typedef unsigned short u16;
typedef __bf16 bf16x8 __attribute__((ext_vector_type(8)));
typedef u16    u16x8  __attribute__((ext_vector_type(8)));
typedef float  f32x4  __attribute__((ext_vector_type(4)));
typedef float  f32x16 __attribute__((ext_vector_type(16)));

__device__ __forceinline__ float b2f(u16 u) {
    union { unsigned u; float f; } x; x.u = ((unsigned)u) << 16; return x.f;
}
__device__ __forceinline__ u16 f2b(float f) {
    union { float f; unsigned u; } x; x.f = f;
    unsigned r = x.u + 0x7FFFu + ((x.u >> 16) & 1u);   // RNE
    return (u16)(r >> 16);
}
__device__ __forceinline__ f32x4 mfma16(bf16x8 a, bf16x8 b, f32x4 c) {
    return __builtin_amdgcn_mfma_f32_16x16x32_bf16(a, b, c, 0, 0, 0);
}
__device__ __forceinline__ f32x16 mfma32(bf16x8 a, bf16x8 b, f32x16 c) {
    return __builtin_amdgcn_mfma_f32_32x32x16_bf16(a, b, c, 0, 0, 0);
}
__device__ __forceinline__ void dma16(const void* g, void* l) {
    __builtin_amdgcn_global_load_lds((const __attribute__((address_space(1))) void*)g,
                                     (__attribute__((address_space(3))) void*)l, 16, 0, 0);
}

#define QSCALE 0.09016844f   // (1/16) * log2(e): softmax in base-2 domain

// ---------------------------------------------------------------- dtype detector
__global__ __launch_bounds__(256) void k_detect(const unsigned* __restrict__ x32, int* __restrict__ flag) {
    __shared__ int cnt;
    if (threadIdx.x == 0) cnt = 0;
    __syncthreads();
    int local = 0;
    for (int i = threadIdx.x; i < 4096; i += 256) {
        unsigned lo = x32[i] & 0xFFFFu;
        unsigned e = (lo >> 7) & 0xFFu;
        if (e >= 0x60u && e <= 0x8Fu) local++;
    }
    atomicAdd(&cnt, local);
    __syncthreads();
    if (threadIdx.x == 0) *flag = (cnt >= 2048) ? 0 : 1;
}

// ---------------------------------------------------------------- x convert
__global__ __launch_bounds__(256) void k_cvtx(const void* __restrict__ src, u16* __restrict__ dst,
                                              const int* __restrict__ flag) {
    const int i = (blockIdx.x * 256 + threadIdx.x) * 4;
    if (*flag) {
        float4 v = *(const float4*)((const float*)src + i);
        u16 o0 = f2b(v.x), o1 = f2b(v.y), o2 = f2b(v.z), o3 = f2b(v.w);
        unsigned lo = (unsigned)o0 | ((unsigned)o1 << 16);
        unsigned hi = (unsigned)o2 | ((unsigned)o3 << 16);
        *(uint2*)(dst + i) = make_uint2(lo, hi);
    } else {
        *(uint2*)(dst + i) = *(const uint2*)((const u16*)src + i);
    }
}

// ---------------------------------------------------------------- params convert
__global__ __launch_bounds__(256) void k_cvtp(const void* s0, const void* s1, const void* s2,
                                              const void* s3, const void* s4, const void* s5,
                                              u16* d0, u16* d1, u16* d2, u16* d3, u16* d4, u16* d5,
                                              const int* __restrict__ flag) {
    const int i = blockIdx.x * 256 + threadIdx.x;
    const int f = *flag;
    const void* s; u16* d; int j;
    if      (i < 256)    { s = s0; d = d0; j = i; }
    else if (i < 512)    { s = s1; d = d1; j = i - 256; }
    else if (i < 197120) { s = s2; d = d2; j = i - 512; }
    else if (i < 197888) { s = s3; d = d3; j = i - 197120; }
    else if (i < 263424) { s = s4; d = d4; j = i - 197888; }
    else if (i < 263680) { s = s5; d = d5; j = i - 263424; }
    else return;
    if (f) d[j] = f2b(((const float*)s)[j]);
    else   d[j] = ((const u16*)s)[j];
}

// ---------------------------------------------------------------- group-norm stats
__global__ __launch_bounds__(256) void k_stats(const u16* __restrict__ x, float* __restrict__ stats) {
    const int bg = blockIdx.x;
    const u16* p = x + (size_t)bg * 131072;
    float s = 0.f, ss = 0.f;
    for (int i = threadIdx.x; i < 16384; i += 256) {
        bf16x8 v = *(const bf16x8*)(p + i * 8);
#pragma unroll
        for (int j = 0; j < 8; j++) { float f = (float)v[j]; s += f; ss += f * f; }
    }
#pragma unroll
    for (int o = 1; o < 64; o <<= 1) { s += __shfl_xor(s, o, 64); ss += __shfl_xor(ss, o, 64); }
    __shared__ float rs[4], rss[4];
    const int wv = threadIdx.x >> 6;
    if ((threadIdx.x & 63) == 0) { rs[wv] = s; rss[wv] = ss; }
    __syncthreads();
    if (threadIdx.x == 0) {
        s = rs[0] + rs[1] + rs[2] + rs[3];
        ss = rss[0] + rss[1] + rss[2] + rss[3];
        float mean = s * (1.f / 131072.f);
        float var = fmaxf(ss * (1.f / 131072.f) - mean * mean, 0.f);
        stats[bg] = mean;
        stats[32 + bg] = rsqrtf(var + 1e-5f);
    }
}

// ---------------------------------------------------------------- normalize + transpose to tokens [b][n][c]
__global__ __launch_bounds__(256) void k_tok(const u16* __restrict__ x, const u16* __restrict__ nw,
                                             const u16* __restrict__ nb, const float* __restrict__ stats,
                                             u16* __restrict__ tok) {
    const int b = blockIdx.z, c0 = blockIdx.y * 64, p0 = blockIdx.x * 64;
    __shared__ u16 t[64][72];
    const int cl = threadIdx.x >> 2, seg = threadIdx.x & 3;
    const int c = c0 + cl;
    const int g = c >> 5;
    const float mean = stats[b * 8 + g], rstd = stats[32 + b * 8 + g];
    const float scale = b2f(nw[c]) * rstd;
    const float shift = b2f(nb[c]) - mean * scale;
    const u16* xp = x + ((size_t)(b * 256 + c)) * 4096 + p0 + seg * 16;
#pragma unroll
    for (int h = 0; h < 2; h++) {
        bf16x8 v = *(const bf16x8*)(xp + h * 8);
#pragma unroll
        for (int j = 0; j < 8; j++)
            t[seg * 16 + h * 8 + j][cl] = f2b((float)v[j] * scale + shift);
    }
    __syncthreads();
    u16x8 o0, o1;
#pragma unroll
    for (int j = 0; j < 8; j++) { o0[j] = t[cl][seg * 16 + j]; o1[j] = t[cl][seg * 16 + 8 + j]; }
    u16* op = tok + ((size_t)(b * 4096 + p0 + cl)) * 256 + c0 + seg * 16;
    *(u16x8*)op = o0;
    *((u16x8*)op + 1) = o1;
}

// ---------------------------------------------------------------- QKV GEMM (swizzled LDS)
// Q pre-scaled by QSCALE; V stored at bit-swapped(2,3) position for direct P^T register feed.
__global__ __launch_bounds__(256) void k_qkv(const u16* __restrict__ A, const u16* __restrict__ W,
                                             const u16* __restrict__ bias,
                                             u16* __restrict__ Qo, u16* __restrict__ Ko, u16* __restrict__ Vt) {
    const int m0 = blockIdx.x * 128, n0 = blockIdx.y * 128;
    const int tid = threadIdx.x, w = tid >> 6, lane = tid & 63, l15 = lane & 15, l4 = lane >> 4;
    const int wm = w >> 1, wn = w & 1;
    __shared__ __attribute__((aligned(16))) u16 At[128 * 64];
    __shared__ __attribute__((aligned(16))) u16 Bt[128 * 64];
    f32x4 acc[4][4];
    const f32x4 z = {0.f, 0.f, 0.f, 0.f};
#pragma unroll
    for (int i = 0; i < 4; i++)
#pragma unroll
        for (int j = 0; j < 4; j++) acc[i][j] = z;

    for (int kt = 0; kt < 4; kt++) {
        const int k0 = kt * 64;
#pragma unroll
        for (int i = 0; i < 4; i++) {
            int v = tid + i * 256;
            int row = v >> 3, c8 = v & 7;
            int swz = (c8 ^ (row & 7)) << 3;
            *(u16x8*)(&At[row * 64 + swz]) = *(const u16x8*)(A + (size_t)(m0 + row) * 256 + k0 + c8 * 8);
            *(u16x8*)(&Bt[row * 64 + swz]) = *(const u16x8*)(W + (size_t)(n0 + row) * 256 + k0 + c8 * 8);
        }
        __syncthreads();
#pragma unroll
        for (int ks = 0; ks < 2; ks++) {
            const int sc = ((ks * 4 + l4) ^ (l15 & 7)) << 3;
            bf16x8 af[4], bfr[4];
#pragma unroll
            for (int i = 0; i < 4; i++) {
                af[i]  = *(const bf16x8*)(&At[(wm * 64 + i * 16 + l15) * 64 + sc]);
                bfr[i] = *(const bf16x8*)(&Bt[(wn * 64 + i * 16 + l15) * 64 + sc]);
            }
#pragma unroll
            for (int i = 0; i < 4; i++)
#pragma unroll
                for (int j = 0; j < 4; j++) acc[i][j] = mfma16(af[i], bfr[j], acc[i][j]);
        }
        __syncthreads();
    }
#pragma unroll
    for (int j = 0; j < 4; j++) {
        const int n = n0 + wn * 64 + j * 16 + l15;
        const float bia = b2f(bias[n]);
#pragma unroll
        for (int i = 0; i < 4; i++) {
#pragma unroll
            for (int r = 0; r < 4; r++) {
                const int m = m0 + wm * 64 + i * 16 + l4 * 4 + r;
                const float vv = acc[i][j][r] + bia;
                if (n < 256)       Qo[(size_t)m * 256 + n] = f2b(vv * QSCALE);
                else if (n < 512)  Ko[(size_t)m * 256 + (n - 256)] = f2b(vv);
                else {
                    const int bb = m >> 12;
                    int p = m & 4095;
                    int d = ((p >> 2) ^ (p >> 3)) & 1;      // swap bits 2<->3
                    p ^= d * 12;
                    Vt[((size_t)bb * 256 + (n - 512)) * 4096 + p] = f2b(vv);
                }
            }
        }
    }
}

// ---------------------------------------------------------------- flash attention v4: S^T trick, register softmax
// grid (32 qtiles, 4 b, 4 splits); block 256 = 4 waves x 32 q; Bc=32; 32 iters.
// S^T = mfma32(K_frag, Q_frag) -> col=lane&31=q. Softmax per-lane in registers.
// P^T feeds PV B-operand directly (V pre-permuted by swap23). Out^T[c][q] in C-layout.
__global__ __launch_bounds__(256, 2) void k_attn(const u16* __restrict__ Q, const u16* __restrict__ K,
                                                 const u16* __restrict__ Vt,
                                                 u16* __restrict__ Up, float* __restrict__ ml) {
    const int qt = blockIdx.x, b = blockIdx.y, sp = blockIdx.z;
    const int tid = threadIdx.x, w = tid >> 6, lane = tid & 63;
    const int l31 = lane & 31, h = lane >> 5;
    const int qcol = qt * 128 + w * 32 + l31;

    __shared__ __attribute__((aligned(16))) u16 KT[32 * 256];   // [j][c], chunk ^ j swizzle
    __shared__ __attribute__((aligned(16))) u16 VT[256 * 32];   // [c][t], chunk ^ (c>>3)&3 swizzle

    // Q as B-operand fragments: n=l31=q, k = kb*16 + h*8 + e  (pre-scaled by QSCALE)
    bf16x8 aq[16];
    {
        const u16* qp = Q + ((size_t)(b * 4096 + qcol)) * 256 + h * 8;
#pragma unroll
        for (int kb = 0; kb < 16; kb++) aq[kb] = *(const bf16x8*)(qp + kb * 16);
    }
    f32x16 acc[8];
#pragma unroll
    for (int ct = 0; ct < 8; ct++)
#pragma unroll
        for (int r = 0; r < 16; r++) acc[ct][r] = 0.f;
    float m_i = -3e38f, l_i = 0.f;   // per-lane (q), replicated across h pair

    const u16* Kg0 = K + (size_t)(b * 4096 + sp * 1024) * 256;
    const u16* Vg0 = Vt + (size_t)b * 256 * 4096 + sp * 1024;

    for (int kt = 0; kt < 32; kt++) {
        // ---- stage K tile [32][256] + V tile [256][32] (16B DMA, swizzle on global side)
        {
            const u16* Kg = Kg0 + (size_t)kt * 32 * 256;
#pragma unroll
            for (int i = 0; i < 4; i++) {
                int q = i * 256 + tid;
                int row = q >> 5, c = q & 31;
                dma16(Kg + row * 256 + ((c ^ row) << 3), &KT[(i * 256 + (tid & 192)) * 8]);
            }
            const u16* Vg = Vg0 + kt * 32;
#pragma unroll
            for (int i = 0; i < 4; i++) {
                int q = i * 256 + tid;
                int row = q >> 2, c = q & 3;
                dma16(Vg + (size_t)row * 4096 + ((c ^ ((row >> 3) & 3)) << 3), &VT[(i * 256 + (tid & 192)) * 8]);
            }
        }
        __syncthreads();   // drains vmcnt + barrier

        // ---- S^T = K Q^T : A=K (LDS), B=Q (regs); C col = q = l31, row j = (r&3)+8(r>>2)+4h
        f32x16 st;
#pragma unroll
        for (int r = 0; r < 16; r++) st[r] = 0.f;
#pragma unroll
        for (int kb = 0; kb < 16; kb++) {
            bf16x8 bk = *(const bf16x8*)(&KT[l31 * 256 + (((kb * 2 + h) ^ l31) << 3)]);
            st = mfma32(bk, aq[kb], st);
        }

        // ---- per-lane online softmax (base-2 domain; Q pre-scaled)
        float mx = st[0];
#pragma unroll
        for (int r = 1; r < 16; r++) mx = fmaxf(mx, st[r]);
        mx = fmaxf(mx, __shfl_xor(mx, 32, 64));
        if (__any(mx > m_i + 4.f)) {           // delayed-max: rare rescale
            const float m_new = fmaxf(m_i, mx);
            const float al = __builtin_amdgcn_exp2f(m_i - m_new);
#pragma unroll
            for (int ct = 0; ct < 8; ct++)
#pragma unroll
                for (int r = 0; r < 16; r++) acc[ct][r] *= al;
            l_i *= al;
            m_i = m_new;
        }
        float sum = 0.f;
#pragma unroll
        for (int r = 0; r < 16; r++) {
            st[r] = __builtin_amdgcn_exp2f(st[r] - m_i);
            sum += st[r];
        }
        sum += __shfl_xor(sum, 32, 64);
        l_i += sum;

        // ---- P^T B-fragments directly from registers (V pre-permuted by swap23)
        union { u16x8 u; bf16x8 bv; } p0, p1;
#pragma unroll
        for (int e = 0; e < 8; e++) { p0.u[e] = f2b(st[e]); p1.u[e] = f2b(st[8 + e]); }

        // ---- acc += V^T P^T : out^T[c][q]
#pragma unroll
        for (int ct = 0; ct < 8; ct++) {
            bf16x8 av0 = *(const bf16x8*)(&VT[(ct * 32 + l31) * 32 + ((h ^ (l31 >> 3)) << 3)]);
            acc[ct] = mfma32(av0, p0.bv, acc[ct]);
            bf16x8 av1 = *(const bf16x8*)(&VT[(ct * 32 + l31) * 32 + (((2 + h) ^ (l31 >> 3)) << 3)]);
            acc[ct] = mfma32(av1, p1.bv, acc[ct]);
        }
        __syncthreads();   // protect tiles before next DMA
    }

    // ---- epilogue: (m,l) + unnormalized partial O^T [c][q]
    if (h == 0)
        ((float2*)ml)[(size_t)(sp * 4 + b) * 4096 + qcol] = make_float2(m_i, l_i);
    u16* up = Up + (size_t)(sp * 4 + b) * 256 * 4096 + qcol;
#pragma unroll
    for (int ct = 0; ct < 8; ct++) {
#pragma unroll
        for (int r = 0; r < 16; r++) {
            const int c = ct * 32 + (r & 3) + 8 * (r >> 2) + 4 * h;
            up[(size_t)c * 4096] = f2b(acc[ct][r]);
        }
    }
}

// ---------------------------------------------------------------- combine k-splits -> Ob [q][c] bf16
__global__ __launch_bounds__(256) void k_comb(const u16* __restrict__ Up, const float* __restrict__ ml,
                                              u16* __restrict__ Ob) {
    const int qt = blockIdx.x, b = blockIdx.y;
    const int tid = threadIdx.x, ql = tid & 63, cg = tid >> 6;
    const int q = qt * 64 + ql;
    __shared__ __attribute__((aligned(16))) u16 T[64 * 256];
    float w_s[4];
    {
        float m_s[4], l_s[4];
#pragma unroll
        for (int s = 0; s < 4; s++) {
            float2 v = ((const float2*)ml)[(size_t)(s * 4 + b) * 4096 + q];
            m_s[s] = v.x; l_s[s] = v.y;
        }
        float M = fmaxf(fmaxf(m_s[0], m_s[1]), fmaxf(m_s[2], m_s[3]));
        float L = 0.f, e[4];
#pragma unroll
        for (int s = 0; s < 4; s++) { e[s] = __builtin_amdgcn_exp2f(m_s[s] - M); L += l_s[s] * e[s]; }
        float inv = 1.f / fmaxf(L, 1e-30f);
#pragma unroll
        for (int s = 0; s < 4; s++) w_s[s] = e[s] * inv;
    }
#pragma unroll
    for (int j8 = 0; j8 < 8; j8++) {
        u16x8 o;
#pragma unroll
        for (int e = 0; e < 8; e++) {
            const int c = cg * 64 + j8 * 8 + e;
            float v = 0.f;
#pragma unroll
            for (int s = 0; s < 4; s++)
                v += b2f(Up[(size_t)((s * 4 + b) * 256 + c) * 4096 + q]) * w_s[s];
            o[e] = f2b(v);
        }
        *(u16x8*)(&T[ql * 256 + (((cg * 8 + j8) ^ (ql & 31)) << 3)]) = o;
    }
    __syncthreads();
    const int ql2 = tid >> 2, cs = tid & 3;
#pragma unroll
    for (int k = 0; k < 8; k++) {
        u16x8 v = *(const u16x8*)(&T[ql2 * 256 + (((cs * 8 + k) ^ (ql2 & 31)) << 3)]);
        *(u16x8*)(Ob + (size_t)(b * 4096 + qt * 64 + ql2) * 256 + cs * 64 + k * 8) = v;
    }
}

// ---------------------------------------------------------------- proj GEMM + residual, store [b][c][p]
__global__ __launch_bounds__(256) void k_proj(const u16* __restrict__ A, const u16* __restrict__ W,
                                              const u16* __restrict__ bias, const u16* __restrict__ x,
                                              void* __restrict__ out, const int* __restrict__ flag) {
    const int f32out = *flag;
    const int m0 = blockIdx.x * 128, n0 = blockIdx.y * 128;
    const int tid = threadIdx.x, w = tid >> 6, lane = tid & 63, l15 = lane & 15, l4 = lane >> 4;
    const int wm = w >> 1, wn = w & 1;
    __shared__ __attribute__((aligned(16))) u16 At[128 * 64];
    __shared__ __attribute__((aligned(16))) u16 Bt[128 * 64];
    f32x4 acc[4][4];
    const f32x4 z = {0.f, 0.f, 0.f, 0.f};
#pragma unroll
    for (int i = 0; i < 4; i++)
#pragma unroll
        for (int j = 0; j < 4; j++) acc[i][j] = z;

    for (int kt = 0; kt < 4; kt++) {
        const int k0 = kt * 64;
#pragma unroll
        for (int i = 0; i < 4; i++) {
            int v = tid + i * 256;
            int row = v >> 3, c8 = v & 7;
            int swz = (c8 ^ (row & 7)) << 3;
            *(u16x8*)(&At[row * 64 + swz]) = *(const u16x8*)(A + (size_t)(m0 + row) * 256 + k0 + c8 * 8);
            *(u16x8*)(&Bt[row * 64 + swz]) = *(const u16x8*)(W + (size_t)(n0 + row) * 256 + k0 + c8 * 8);
        }
        __syncthreads();
#pragma unroll
        for (int ks = 0; ks < 2; ks++) {
            const int sc = ((ks * 4 + l4) ^ (l15 & 7)) << 3;
            bf16x8 af[4], bfr[4];
#pragma unroll
            for (int i = 0; i < 4; i++) {
                af[i]  = *(const bf16x8*)(&At[(wm * 64 + i * 16 + l15) * 64 + sc]);
                bfr[i] = *(const bf16x8*)(&Bt[(wn * 64 + i * 16 + l15) * 64 + sc]);
            }
#pragma unroll
            for (int i = 0; i < 4; i++)
#pragma unroll
                for (int j = 0; j < 4; j++) acc[i][j] = mfma16(af[i], bfr[j], acc[i][j]);
        }
        __syncthreads();
    }
#pragma unroll
    for (int j = 0; j < 4; j++) {
        const int n = n0 + wn * 64 + j * 16 + l15;
        const float bia = b2f(bias[n]);
#pragma unroll
        for (int i = 0; i < 4; i++) {
#pragma unroll
            for (int r = 0; r < 4; r++) {
                const int m = m0 + wm * 64 + i * 16 + l4 * 4 + r;
                const int bb = m >> 12, p = m & 4095;
                const size_t oi = ((size_t)bb * 256 + n) * 4096 + p;
                const float v = b2f(x[oi]) + acc[i][j][r] + bia;
                if (f32out) ((float*)out)[oi] = v;
                else        ((u16*)out)[oi] = f2b(v);
            }
        }
    }
}

extern "C" void kernel_launch(void* const* d_in, const int* in_sizes, int n_in,
                              void* d_out, int out_size, void* d_ws, size_t ws_size,
                              hipStream_t stream) {
    char* ws = (char*)d_ws;
    float* stats = (float*)ws;
    int*   flag  = (int*)(ws + 2048);
    u16* xb  = (u16*)(ws + 4096);                                // 4194304 u16
    u16* nwb = xb + (size_t)4194304;
    u16* nbb = nwb + 256;
    u16* qbb = nbb + 256;
    u16* pbb = qbb + 768;
    u16* pad = pbb + 256;
    u16* qwb = pad + 256;                                        // 196608
    u16* pwb = qwb + (size_t)196608;                             // 65536
    u16* tok = pwb + (size_t)65536;                              // [16384][256], reused as Ob
    u16* Qb  = tok + (size_t)16384 * 256;
    u16* Kb  = Qb  + (size_t)16384 * 256;
    u16* Vb  = Kb  + (size_t)16384 * 256;                        // [4][256][4096] (pos bit-swapped)
    u16* Upb = Vb  + (size_t)16384 * 256;                        // [4][4][256][4096] bf16 partials
    float* mlb = (float*)(Upb + (size_t)4 * 4 * 256 * 4096);     // [4][4][4096] float2
    u16* Ob  = tok;

    k_detect<<<dim3(1), dim3(256), 0, stream>>>((const unsigned*)d_in[0], flag);
    k_cvtx<<<dim3(4096), dim3(256), 0, stream>>>(d_in[0], xb, flag);
    k_cvtp<<<dim3(1030), dim3(256), 0, stream>>>(d_in[1], d_in[2], d_in[3], d_in[4], d_in[5], d_in[6],
                                                 nwb, nbb, qwb, qbb, pwb, pbb, flag);

    k_stats<<<dim3(32), dim3(256), 0, stream>>>(xb, stats);
    k_tok  <<<dim3(64, 4, 4), dim3(256), 0, stream>>>(xb, nwb, nbb, stats, tok);
    k_qkv  <<<dim3(128, 6), dim3(256), 0, stream>>>(tok, qwb, qbb, Qb, Kb, Vb);
    k_attn <<<dim3(32, 4, 4), dim3(256), 0, stream>>>(Qb, Kb, Vb, Upb, mlb);
    k_comb <<<dim3(64, 4), dim3(256), 0, stream>>>(Upb, mlb, Ob);
    k_proj <<<dim3(128, 2), dim3(256), 0, stream>>>(Ob, pwb, pbb, xb, d_out, flag);
}